// Round 4
// baseline (746.230 us; speedup 1.0000x reference)
//
#include <hip/hip_runtime.h>
#include <cmath>

#define B_ROWS 16384
#define IN_DIM 784
#define N_HID  2000
#define K_WIN  200

// ---------------------------------------------------------------------------
// Phase 0a: boost[i] = expf(0.1f - duty[i])
// ---------------------------------------------------------------------------
__global__ __launch_bounds__(256) void boost_kernel(const float* __restrict__ duty,
                                                    float* __restrict__ boost) {
    int i = blockIdx.x * 256 + threadIdx.x;
    if (i < N_HID) boost[i] = expf(0.1f - duty[i]);
}

// ---------------------------------------------------------------------------
// Phase 0b: w2t[i*12 + c] = w2[c*2000 + i]
// ---------------------------------------------------------------------------
__global__ __launch_bounds__(256) void w2t_kernel(const float* __restrict__ w2,
                                                  float* __restrict__ w2t) {
    int t = blockIdx.x * 256 + threadIdx.x;
    if (t < N_HID * 10) {
        int i = t / 10, c = t - i * 10;
        w2t[i * 12 + c] = w2[c * N_HID + i];
    }
}

// ---------------------------------------------------------------------------
// Phase 1: h = x @ W1^T + b1, fp32.  128x128 tile, BK=16, 256 threads,
// 8x8 microtile (split 4+4).  SOFTWARE-PIPELINED: prefetch next K-tile into
// registers right after the (single) barrier, compute current tile from the
// other LDS buffer -> global-load latency overlaps the 1024-FMA loop.
// Per-output k-summation order identical to rounds 2/3 (bit-identical h).
// ---------------------------------------------------------------------------
__global__ __launch_bounds__(256) void gemm_fp32_kernel(const float* __restrict__ x,
                                                        const float* __restrict__ w1,
                                                        const float* __restrict__ b1,
                                                        float* __restrict__ h) {
    __shared__ float As[2][16][132] __attribute__((aligned(16)));   // [buf][k][m]
    __shared__ float Bs[2][16][132] __attribute__((aligned(16)));   // [buf][k][n]
    const int tid = threadIdx.x;
    const int n0 = blockIdx.x * 128;
    const int m0 = blockIdx.y * 128;
    const int tx = tid & 15;        // n microtile
    const int ty = tid >> 4;        // m microtile
    const int r  = tid >> 2;        // 0..63 staging row
    const int c  = (tid & 3) << 2;  // 0,4,8,12 staging k-offset

    const int nb0 = n0 + r;
    const int nb1 = (n0 + r + 64 < N_HID) ? (n0 + r + 64) : (N_HID - 1);

    const float* xp0 = x  + (size_t)(m0 + r)      * IN_DIM + c;
    const float* xp1 = x  + (size_t)(m0 + r + 64) * IN_DIM + c;
    const float* wp0 = w1 + (size_t)nb0           * IN_DIM + c;
    const float* wp1 = w1 + (size_t)nb1           * IN_DIM + c;

    float4 pa0 = *(const float4*)(xp0);
    float4 pa1 = *(const float4*)(xp1);
    float4 pb0 = *(const float4*)(wp0);
    float4 pb1 = *(const float4*)(wp1);

    float acc[8][8] = {};
    int buf = 0;

    for (int k0 = 0; k0 < IN_DIM; k0 += 16) {
        float (*A)[132] = As[buf];
        float (*Bv)[132] = Bs[buf];
        // stage prefetched regs into LDS[buf] (safe pre-barrier: see dbuf proof)
        A[c + 0][r] = pa0.x;  A[c + 1][r] = pa0.y;  A[c + 2][r] = pa0.z;  A[c + 3][r] = pa0.w;
        A[c + 0][r + 64] = pa1.x;  A[c + 1][r + 64] = pa1.y;  A[c + 2][r + 64] = pa1.z;  A[c + 3][r + 64] = pa1.w;
        Bv[c + 0][r] = pb0.x;  Bv[c + 1][r] = pb0.y;  Bv[c + 2][r] = pb0.z;  Bv[c + 3][r] = pb0.w;
        Bv[c + 0][r + 64] = pb1.x; Bv[c + 1][r + 64] = pb1.y; Bv[c + 2][r + 64] = pb1.z; Bv[c + 3][r + 64] = pb1.w;
        __syncthreads();

        // issue next tile's global loads NOW; latency hides under the FMA loop
        const int kn = (k0 + 16 < IN_DIM) ? (k0 + 16) : 0;  // last-iter dummy
        pa0 = *(const float4*)(xp0 + kn);
        pa1 = *(const float4*)(xp1 + kn);
        pb0 = *(const float4*)(wp0 + kn);
        pb1 = *(const float4*)(wp1 + kn);

        #pragma unroll
        for (int kk = 0; kk < 16; ++kk) {
            float a[8], b[8];
            *(float4*)&a[0] = *(const float4*)&A[kk][ty * 4];
            *(float4*)&a[4] = *(const float4*)&A[kk][64 + ty * 4];
            *(float4*)&b[0] = *(const float4*)&Bv[kk][tx * 4];
            *(float4*)&b[4] = *(const float4*)&Bv[kk][64 + tx * 4];
            #pragma unroll
            for (int i = 0; i < 8; ++i)
                #pragma unroll
                for (int j = 0; j < 8; ++j)
                    acc[i][j] = fmaf(a[i], b[j], acc[i][j]);
        }
        buf ^= 1;
    }

    const int nlo = n0 + tx * 4;        // <= 1983: unguarded
    const int nhi = n0 + 64 + tx * 4;   // may exceed: guarded
    #pragma unroll
    for (int i = 0; i < 8; ++i) {
        const int m = m0 + ((i < 4) ? (ty * 4 + i) : (64 + ty * 4 + (i - 4)));
        float* hrow = h + (size_t)m * N_HID;
        float4 v;
        v.x = acc[i][0] + b1[nlo + 0];
        v.y = acc[i][1] + b1[nlo + 1];
        v.z = acc[i][2] + b1[nlo + 2];
        v.w = acc[i][3] + b1[nlo + 3];
        *(float4*)(hrow + nlo) = v;
        if (nhi + 3 < N_HID) {
            float4 w;
            w.x = acc[i][4] + b1[nhi + 0];
            w.y = acc[i][5] + b1[nhi + 1];
            w.z = acc[i][6] + b1[nhi + 2];
            w.w = acc[i][7] + b1[nhi + 3];
            *(float4*)(hrow + nhi) = w;
        } else {
            #pragma unroll
            for (int j = 0; j < 4; ++j)
                if (nhi + j < N_HID) hrow[nhi + j] = acc[i][4 + j] + b1[nhi + j];
        }
    }
}

// ---------------------------------------------------------------------------
// Phase 2: one row per wave, zero __syncthreads (unchanged from round 3).
// ---------------------------------------------------------------------------
__global__ __launch_bounds__(256) void topk_logits_kernel(const float* __restrict__ h,
                                                          const float* __restrict__ boost,
                                                          const float* __restrict__ w2t,
                                                          const float* __restrict__ b2,
                                                          float* __restrict__ out) {
    __shared__ unsigned shist[4 * 256] __attribute__((aligned(16)));
    const int wv   = threadIdx.x >> 6;
    const int lane = threadIdx.x & 63;
    const int row  = blockIdx.x * 4 + wv;
    unsigned* hist = &shist[wv * 256];

    const float* hrow = h + (size_t)row * N_HID;
    float4 hreg[8];
    unsigned key[8][4];

    #pragma unroll
    for (int s = 0; s < 8; ++s) {
        const int idx4 = s * 64 + lane;
        if (idx4 < N_HID / 4) {
            float4 hv = *(const float4*)(hrow + idx4 * 4);
            float4 bv = *(const float4*)(boost + idx4 * 4);
            hreg[s] = hv;
            unsigned u0 = __float_as_uint(hv.x * bv.x);
            unsigned u1 = __float_as_uint(hv.y * bv.y);
            unsigned u2 = __float_as_uint(hv.z * bv.z);
            unsigned u3 = __float_as_uint(hv.w * bv.w);
            key[s][0] = (u0 >> 31) ? ~u0 : (u0 | 0x80000000u);
            key[s][1] = (u1 >> 31) ? ~u1 : (u1 | 0x80000000u);
            key[s][2] = (u2 >> 31) ? ~u2 : (u2 | 0x80000000u);
            key[s][3] = (u3 >> 31) ? ~u3 : (u3 | 0x80000000u);
        } else {
            hreg[s] = make_float4(0.f, 0.f, 0.f, 0.f);
            key[s][0] = key[s][1] = key[s][2] = key[s][3] = 0u;
        }
    }

    unsigned pref = 0u;
    int r = K_WIN;

    #pragma unroll
    for (int pass = 3; pass >= 0; --pass) {
        const int shift = pass * 8;
        const unsigned himask = (pass == 3) ? 0u : (0xFFFFFFFFu << (shift + 8));
        hist[lane] = 0u; hist[lane + 64] = 0u; hist[lane + 128] = 0u; hist[lane + 192] = 0u;
        __builtin_amdgcn_wave_barrier();
        #pragma unroll
        for (int s = 0; s < 8; ++s)
            #pragma unroll
            for (int j = 0; j < 4; ++j) {
                unsigned k = key[s][j];
                if (((k ^ pref) & himask) == 0u)
                    atomicAdd(&hist[(k >> shift) & 255u], 1u);
            }
        __builtin_amdgcn_wave_barrier();
        uint4 hv = *(const uint4*)&hist[lane * 4];
        unsigned tot = hv.x + hv.y + hv.z + hv.w;
        unsigned run = tot;
        #pragma unroll
        for (int off = 1; off < 64; off <<= 1) {
            unsigned t = (unsigned)__shfl_down((int)run, off);
            if (lane + off < 64) run += t;
        }
        const int above = (int)(run - tot);
        const int i3 = above + (int)hv.w;
        const int i2 = i3 + (int)hv.z;
        const int i1 = i2 + (int)hv.y;
        const int i0 = i1 + (int)hv.x;
        int fq = -1, fex = 0;
        if (i0 >= r && i1 < r)    { fq = 0; fex = i1; }
        if (i1 >= r && i2 < r)    { fq = 1; fex = i2; }
        if (i2 >= r && i3 < r)    { fq = 2; fex = i3; }
        if (i3 >= r && above < r) { fq = 3; fex = above; }
        unsigned long long fm = __ballot(fq >= 0);
        int src = __builtin_ctzll(fm);
        unsigned pack = (fq >= 0)
            ? (((unsigned)(lane * 4 + fq) << 16) | (unsigned)(r - fex)) : 0u;
        pack = (unsigned)__shfl((int)pack, src);
        pref |= (pack >> 16) << shift;
        r = (int)(pack & 0xFFFFu);
    }

    const unsigned tkey = pref;
    const int take_eq = r;

    unsigned winm = 0u;
    int run_eq = 0;
    #pragma unroll
    for (int s = 0; s < 8; ++s) {
        bool gt[4], eq[4];
        #pragma unroll
        for (int j = 0; j < 4; ++j) {
            unsigned k = key[s][j];
            gt[j] = (k > tkey);
            eq[j] = (k == tkey);
        }
        unsigned long long em0 = __ballot(eq[0]);
        unsigned long long em1 = __ballot(eq[1]);
        unsigned long long em2 = __ballot(eq[2]);
        unsigned long long em3 = __ballot(eq[3]);
        const unsigned long long lt = (1ull << lane) - 1ull;
        const int base_lt = __popcll(em0 & lt) + __popcll(em1 & lt) +
                            __popcll(em2 & lt) + __popcll(em3 & lt);
        int own = 0;
        #pragma unroll
        for (int j = 0; j < 4; ++j) {
            if (gt[j]) winm |= 1u << (s * 4 + j);
            else if (eq[j]) {
                if (run_eq + base_lt + own < take_eq) winm |= 1u << (s * 4 + j);
                ++own;
            }
        }
        run_eq += __popcll(em0) + __popcll(em1) + __popcll(em2) + __popcll(em3);
    }

    float l[10];
    #pragma unroll
    for (int cc = 0; cc < 10; ++cc) l[cc] = 0.f;
    #pragma unroll
    for (int s = 0; s < 8; ++s) {
        const int idx4 = s * 64 + lane;
        const float* hp = (const float*)&hreg[s];
        #pragma unroll
        for (int j = 0; j < 4; ++j) {
            if (winm & (1u << (s * 4 + j))) {
                const float hv = hp[j];
                const float* wr = w2t + (size_t)(idx4 * 4 + j) * 12;
                float4 wa = *(const float4*)wr;
                float4 wb = *(const float4*)(wr + 4);
                float2 wc = *(const float2*)(wr + 8);
                l[0] = fmaf(hv, wa.x, l[0]);
                l[1] = fmaf(hv, wa.y, l[1]);
                l[2] = fmaf(hv, wa.z, l[2]);
                l[3] = fmaf(hv, wa.w, l[3]);
                l[4] = fmaf(hv, wb.x, l[4]);
                l[5] = fmaf(hv, wb.y, l[5]);
                l[6] = fmaf(hv, wb.z, l[6]);
                l[7] = fmaf(hv, wb.w, l[7]);
                l[8] = fmaf(hv, wc.x, l[8]);
                l[9] = fmaf(hv, wc.y, l[9]);
            }
        }
    }
    #pragma unroll
    for (int off = 32; off > 0; off >>= 1)
        #pragma unroll
        for (int cc = 0; cc < 10; ++cc)
            l[cc] += __shfl_down(l[cc], off);

    if (lane == 0) {
        float lg[10];
        #pragma unroll
        for (int cc = 0; cc < 10; ++cc) lg[cc] = l[cc] + b2[cc];
        float mx = lg[0];
        #pragma unroll
        for (int cc = 1; cc < 10; ++cc) mx = fmaxf(mx, lg[cc]);
        float s = 0.f;
        #pragma unroll
        for (int cc = 0; cc < 10; ++cc) s += expf(lg[cc] - mx);
        const float lse = mx + logf(s);
        float* orow = out + (size_t)row * 10;
        #pragma unroll
        for (int cc = 0; cc < 10; ++cc) orow[cc] = lg[cc] - lse;
    }
}

// ---------------------------------------------------------------------------
extern "C" void kernel_launch(void* const* d_in, const int* in_sizes, int n_in,
                              void* d_out, int out_size, void* d_ws, size_t ws_size,
                              hipStream_t stream) {
    const float* x    = (const float*)d_in[0];
    const float* w1   = (const float*)d_in[1];
    const float* b1   = (const float*)d_in[2];
    const float* w2   = (const float*)d_in[3];
    const float* b2   = (const float*)d_in[4];
    const float* duty = (const float*)d_in[5];
    float* out = (float*)d_out;

    const size_t hbytes = (size_t)B_ROWS * N_HID * sizeof(float);  // 131.072 MB
    float* h     = (float*)d_ws;
    float* boost = (float*)((char*)d_ws + hbytes);                 // 8 KB
    float* w2t   = (float*)((char*)d_ws + hbytes + 8192);          // 96 KB

    boost_kernel<<<8, 256, 0, stream>>>(duty, boost);
    w2t_kernel<<<(N_HID * 10 + 255) / 256, 256, 0, stream>>>(w2, w2t);
    gemm_fp32_kernel<<<dim3(16, 128), 256, 0, stream>>>(x, w1, b1, h);
    topk_logits_kernel<<<B_ROWS / 4, 256, 0, stream>>>(h, boost, w2t, b2, out);
}